// Round 7
// baseline (259.643 us; speedup 1.0000x reference)
//
#include <hip/hip_runtime.h>
#include <hip/hip_bf16.h>
#include <cstddef>
#include <cstdint>

// Problem constants: B=4, T=2048, C=1024, NH=16, hs=64, M = B*T = 8192
#define B_DIM 4
#define T_DIM 2048
#define C_DIM 1024
#define NHEAD 16
#define HS    64
#define QKV_LD 3072   // fused QKV row stride (3*C)

// log2(e)/8 : folded into the Wq bf16 cast so QK^T emerges in exp2-domain.
#define QSCALE 0.18033688011112042f

typedef __attribute__((ext_vector_type(8))) short short8;   // 8 bf16 (MFMA A/B frag)
typedef __attribute__((ext_vector_type(4))) float f32x4;    // MFMA C/D frag

__device__ __forceinline__ short f2bf(float x) {
    __hip_bfloat16 b = __float2bfloat16(x);   // RNE
    return *reinterpret_cast<short*>(&b);
}

// async global->LDS, 16B per lane; LDS dest is wave-uniform base + lane*16.
__device__ __forceinline__ void load_lds16(const void* g, void* l) {
    __builtin_amdgcn_global_load_lds(
        (const __attribute__((address_space(1))) void*)(g),
        (__attribute__((address_space(3))) void*)(l),
        16, 0, 0);
}

// ---------------------------------------------------------------------------
// cast fp32 -> bf16 (with optional fp32 pre-scale), 8 elements/thread
// ---------------------------------------------------------------------------
__global__ __launch_bounds__(256) void cast_bf16(
    const float* __restrict__ in, short* __restrict__ out, int n8, float scale)
{
    int i = blockIdx.x * 256 + threadIdx.x;
    if (i >= n8) return;
    const float4* p = (const float4*)in + (size_t)i * 2;
    float4 a = p[0], b = p[1];
    short8 o;
    o[0]=f2bf(a.x*scale); o[1]=f2bf(a.y*scale); o[2]=f2bf(a.z*scale); o[3]=f2bf(a.w*scale);
    o[4]=f2bf(b.x*scale); o[5]=f2bf(b.y*scale); o[6]=f2bf(b.z*scale); o[7]=f2bf(b.w*scale);
    *((short8*)out + i) = o;
}

// 4 weight matrices (Wq|Wk|Wv|Wo) -> one contiguous bf16 region (W3b|Wob).
// blockIdx.y selects source; Wq gets QSCALE folded in.
__global__ __launch_bounds__(256) void cast4_bf16(
    const float* __restrict__ w0, const float* __restrict__ w1,
    const float* __restrict__ w2, const float* __restrict__ w3,
    short* __restrict__ out, int n8)
{
    int i = blockIdx.x * 256 + threadIdx.x;
    if (i >= n8) return;
    const int sel = blockIdx.y;
    const float* in = (sel == 0) ? w0 : (sel == 1) ? w1 : (sel == 2) ? w2 : w3;
    const float scale = (sel == 0) ? QSCALE : 1.0f;
    const float4* p = (const float4*)in + (size_t)i * 2;
    float4 a = p[0], b = p[1];
    short8 o;
    o[0]=f2bf(a.x*scale); o[1]=f2bf(a.y*scale); o[2]=f2bf(a.z*scale); o[3]=f2bf(a.w*scale);
    o[4]=f2bf(b.x*scale); o[5]=f2bf(b.y*scale); o[6]=f2bf(b.z*scale); o[7]=f2bf(b.w*scale);
    *((short8*)out + (size_t)sel * n8 + i) = o;
}

// ---------------------------------------------------------------------------
// 8-phase-style MFMA GEMM, BM=128 x BN=256 (grid-divisibility variant):
// C[M,N] = A[M,K] @ B[N,K]^T, bf16 in, fp32 accum, bf16 or fp32 out.
// BK=64, 8 waves (2M x 4N), 512 threads, per-wave 64x64 = acc[4][4].
// LDS 96 KiB double-buffered; grids are exact multiples of 256 (full rounds).
// ---------------------------------------------------------------------------
template<bool OUT_BF16>
__global__ __launch_bounds__(512, 2) void gemm_bt_8ph(
    const short* __restrict__ A,    // [M,K] bf16
    const short* __restrict__ Bm,   // [N,K] bf16
    void* __restrict__ Cm,          // [M,N]
    int M, int N, int K)
{
    __shared__ __align__(16) short lds[49152];   // 96 KiB

    // bijective XCD swizzle (gridDim.x % 8 == 0), then flat -> (bx,by)
    const int nbx = N >> 8;
    int wg = blockIdx.x;
    const int cpx = gridDim.x >> 3;
    wg = (wg & 7) * cpx + (wg >> 3);
    const int bx = wg % nbx, by = wg / nbx;
    const int m0 = by << 7, n0 = bx << 8;        // BM=128, BN=256

    const int t = threadIdx.x;
    const int w = t >> 6, lane = t & 63;
    const int l16 = lane & 15, quad = lane >> 4;
    const int wm = w >> 2, wn = w & 3;           // 2M x 4N waves

    // staging geometry: one call = 64 rows x 128B; thread -> (row, 16B chunk)
    const int rcall  = t >> 3;                   // 0..63
    const int schunk = (t & 7) ^ (rcall & 7);    // pre-swizzled source chunk
    const int dstoff = w * 512;                  // per-wave LDS base (w*8 rows * 64)

    const short* Ag = A  + (size_t)(m0 + rcall) * K + schunk * 8;
    const short* Bg = Bm + (size_t)(n0 + rcall) * K + schunk * 8;

    short* const Ab0 = lds;
    short* const Ab1 = lds + 8192;
    short* const Bb0 = lds + 16384;
    short* const Bb1 = lds + 32768;

    // frag read offsets (shorts), swizzled
    int aoff[4][2], boff[4][2];
    #pragma unroll
    for (int mf = 0; mf < 4; ++mf) {
        const int ar = wm * 64 + mf * 16 + l16;          // 0..127
        #pragma unroll
        for (int ks = 0; ks < 2; ++ks)
            aoff[mf][ks] = ar * 64 + (((ks * 4 + quad) ^ (ar & 7)) * 8);
    }
    #pragma unroll
    for (int nf = 0; nf < 4; ++nf) {
        const int br = wn * 64 + nf * 16 + l16;          // 0..255
        #pragma unroll
        for (int ks = 0; ks < 2; ++ks)
            boff[nf][ks] = br * 64 + (((ks * 4 + quad) ^ (br & 7)) * 8);
    }

    f32x4 acc[4][4];
    const f32x4 zero4 = {0.f, 0.f, 0.f, 0.f};
    #pragma unroll
    for (int mf = 0; mf < 4; ++mf)
        #pragma unroll
        for (int nf = 0; nf < 4; ++nf) acc[mf][nf] = zero4;

    const int NT = K >> 6;   // 64-wide K-tiles

    // one 64-row staging call
    #define ST64(gb, kt, ro, lb)                                               \
        load_lds16((gb) + (size_t)(ro) * K + (size_t)(kt) * 64,                \
                   (lb) + (ro) * 64 + dstoff)

    // prologue: t0.A (2), t0.B (4), t1.A (2)  -> 8 outstanding
    ST64(Ag, 0, 0, Ab0); ST64(Ag, 0, 64, Ab0);
    ST64(Bg, 0, 0, Bb0); ST64(Bg, 0, 64, Bb0);
    ST64(Bg, 0, 128, Bb0); ST64(Bg, 0, 192, Bb0);
    ST64(Ag, 1, 0, Ab1); ST64(Ag, 1, 64, Ab1);

    for (int kt = 0; kt < NT; ++kt) {
        short* Acur = (kt & 1) ? Ab1 : Ab0;
        short* Bcur = (kt & 1) ? Bb1 : Bb0;
        short* Bnx  = (kt & 1) ? Bb0 : Bb1;

        if (kt == NT - 1) asm volatile("s_waitcnt vmcnt(0)" ::: "memory");
        else              asm volatile("s_waitcnt vmcnt(2)" ::: "memory");
        __builtin_amdgcn_s_barrier();

        // ---- phase 0: B-frags (whole tile) + A-frags mf0,1 ----
        short8 bfr[4][2], af[2][2];
        #pragma unroll
        for (int nf = 0; nf < 4; ++nf)
            #pragma unroll
            for (int ks = 0; ks < 2; ++ks)
                bfr[nf][ks] = *(const short8*)(Bcur + boff[nf][ks]);
        #pragma unroll
        for (int mf = 0; mf < 2; ++mf)
            #pragma unroll
            for (int ks = 0; ks < 2; ++ks)
                af[mf][ks] = *(const short8*)(Acur + aoff[mf][ks]);

        if (kt + 1 < NT) { ST64(Bg, kt + 1, 0, Bnx); ST64(Bg, kt + 1, 64, Bnx); }

        __builtin_amdgcn_s_barrier();
        __builtin_amdgcn_s_setprio(1);
        #pragma unroll
        for (int mf = 0; mf < 2; ++mf)
            #pragma unroll
            for (int nf = 0; nf < 4; ++nf)
                #pragma unroll
                for (int ks = 0; ks < 2; ++ks)
                    acc[mf][nf] = __builtin_amdgcn_mfma_f32_16x16x32_bf16(
                        af[mf][ks], bfr[nf][ks], acc[mf][nf], 0, 0, 0);
        __builtin_amdgcn_s_setprio(0);
        __builtin_amdgcn_s_barrier();

        // ---- phase 1: A-frags mf2,3 ----
        short8 af2[2][2];
        #pragma unroll
        for (int mf = 0; mf < 2; ++mf)
            #pragma unroll
            for (int ks = 0; ks < 2; ++ks)
                af2[mf][ks] = *(const short8*)(Acur + aoff[2 + mf][ks]);

        if (kt + 1 < NT) { ST64(Bg, kt + 1, 128, Bnx); ST64(Bg, kt + 1, 192, Bnx); }

        __builtin_amdgcn_s_barrier();
        __builtin_amdgcn_s_setprio(1);
        #pragma unroll
        for (int mf = 0; mf < 2; ++mf)
            #pragma unroll
            for (int nf = 0; nf < 4; ++nf)
                #pragma unroll
                for (int ks = 0; ks < 2; ++ks)
                    acc[2 + mf][nf] = __builtin_amdgcn_mfma_f32_16x16x32_bf16(
                        af2[mf][ks], bfr[nf][ks], acc[2 + mf][nf], 0, 0, 0);
        __builtin_amdgcn_s_setprio(0);
        __builtin_amdgcn_s_barrier();

        // tail: just-freed A buffer -> prefetch (t+2).A
        if (kt + 2 < NT) {
            short* Aw = (kt & 1) ? Ab1 : Ab0;
            ST64(Ag, kt + 2, 0, Aw); ST64(Ag, kt + 2, 64, Aw);
        }
    }
    #undef ST64

    #pragma unroll
    for (int mf = 0; mf < 4; ++mf) {
        const int row_base = m0 + wm * 64 + mf * 16 + quad * 4;
        #pragma unroll
        for (int nf = 0; nf < 4; ++nf) {
            const int col = n0 + wn * 64 + nf * 16 + l16;
            #pragma unroll
            for (int r = 0; r < 4; ++r) {
                const size_t idx = (size_t)(row_base + r) * N + col;
                if (OUT_BF16) ((short*)Cm)[idx] = f2bf(acc[mf][nf][r]);
                else          ((float*)Cm)[idx] = acc[mf][nf][r];
            }
        }
    }
}

// ---------------------------------------------------------------------------
// Transpose V: bf16 [B,T,srcLD] (head-interleaved cols) -> bf16 [B,NH,HS,T]
// ---------------------------------------------------------------------------
__global__ __launch_bounds__(256) void transpose_v(
    const short* __restrict__ Vb,
    short* __restrict__ Vt, int srcLD)
{
    const int t0 = blockIdx.x * 64;
    const int head = blockIdx.y;              // b*NHEAD + h
    const int b = head >> 4, h = head & 15;

    __shared__ short Ls[64][72];

    const int t = threadIdx.x;
    const int r = t >> 2;
    const int c = (t & 3) * 16;

    const short* src = Vb + ((size_t)(b * T_DIM) + t0 + r) * srcLD + h * HS + c;
    *(short8*)&Ls[r][c]     = *(const short8*)src;
    *(short8*)&Ls[r][c + 8] = *(const short8*)(src + 8);
    __syncthreads();

    short tmp[16];
    #pragma unroll
    for (int i = 0; i < 16; ++i) tmp[i] = Ls[c + i][r];
    short* dst = Vt + ((size_t)head * HS + r) * T_DIM + t0 + c;
    *(short8*)dst       = *(short8*)&tmp[0];
    *(short8*)(dst + 8) = *(short8*)&tmp[8];
}

// ---------------------------------------------------------------------------
// Flash attention v7: R2 structure ([64][72] padded LDS — the benign-2-way
// layout that beat the XOR swizzle) with QSUB=2 for occupancy:
//   grid = 1024 blocks = 4 blocks/CU (launch_bounds(256,4), VGPR<=128),
//   double the resident waves to hide the QK->exp->PV dependency chains.
//  - Q pre-scaled by log2(e)/8 at the Wq cast -> exp is a bare v_exp_f32.
//  - Row-sum l computed by MFMA against a ones B-fragment.
// One block = one (b,h) head x 128 q-rows (2 subtiles of 64); 4 waves.
// S^T trick: A=K-frag, B=Q-frag -> D[key][q]; K rows permuted kappa^-1 so
// exp'd S^T regs concatenate directly into the PV A-fragment. No-max softmax.
// ---------------------------------------------------------------------------
#define QSUB 2

__global__ __launch_bounds__(256, 4) void attn_mfma3(
    const short* __restrict__ Qb,    // [B,T,QKV_LD], Q cols (pre-scaled)
    const short* __restrict__ Kb,    // [B,T,QKV_LD], K cols
    const short* __restrict__ Vt,    // [B*NH, HS, T]
    short* __restrict__ O)           // [B,T,C] bf16
{
    const int i0   = blockIdx.x * (64 * QSUB);
    const int head = blockIdx.y;
    const int b = head >> 4, h = head & 15;

    const int t    = threadIdx.x;
    const int w    = t >> 6;
    const int lane = t & 63;
    const int l16  = lane & 15;
    const int quad = lane >> 4;

    __shared__ short Ks[64][72];     // [perm key][dim]
    __shared__ short Vts[64][72];    // [dim][key]

    short8 qf[QSUB][2];
    #pragma unroll
    for (int sub = 0; sub < QSUB; ++sub) {
        const short* qrow = Qb
            + ((size_t)(b * T_DIM) + i0 + sub * 64 + w * 16 + l16) * QKV_LD + h * HS;
        qf[sub][0] = *(const short8*)(qrow + quad * 8);
        qf[sub][1] = *(const short8*)(qrow + 32 + quad * 8);
    }

    short8 onesv;
    #pragma unroll
    for (int j = 0; j < 8; ++j) onesv[j] = (short)0x3F80;

    const f32x4 zero4 = {0.f, 0.f, 0.f, 0.f};
    f32x4 oacc[QSUB][4];
    f32x4 lacc[QSUB];
    #pragma unroll
    for (int sub = 0; sub < QSUB; ++sub) {
        #pragma unroll
        for (int dg = 0; dg < 4; ++dg) oacc[sub][dg] = zero4;
        lacc[sub] = zero4;
    }

    const int sr = t >> 2;
    const int sc = (t & 3) * 16;
    const int krow = (sr & 32) | ((sr & 4) << 2) | ((sr & 24) >> 1) | (sr & 3);
    const short* kgbase = Kb + (size_t)(b * T_DIM) * QKV_LD + h * HS;
    const short* vgbase = Vt + ((size_t)head * HS + sr) * T_DIM;

    for (int j0 = 0; j0 < T_DIM; j0 += 64) {
        __syncthreads();
        {
            const short* kp = kgbase + (size_t)(j0 + sr) * QKV_LD + sc;
            *(short8*)&Ks[krow][sc]     = *(const short8*)kp;
            *(short8*)&Ks[krow][sc + 8] = *(const short8*)(kp + 8);
            const short* vp = vgbase + j0 + sc;
            *(short8*)&Vts[sr][sc]      = *(const short8*)vp;
            *(short8*)&Vts[sr][sc + 8]  = *(const short8*)(vp + 8);
        }
        __syncthreads();

        // K/V MFMA fragments: read once, reuse for both q-subtiles
        short8 ka[4][2], va[4][2];
        #pragma unroll
        for (int kt = 0; kt < 4; ++kt) {
            ka[kt][0] = *(const short8*)&Ks[kt * 16 + l16][quad * 8];
            ka[kt][1] = *(const short8*)&Ks[kt * 16 + l16][32 + quad * 8];
            va[kt][0] = *(const short8*)&Vts[kt * 16 + l16][quad * 8];
            va[kt][1] = *(const short8*)&Vts[kt * 16 + l16][32 + quad * 8];
        }

        #pragma unroll
        for (int sub = 0; sub < QSUB; ++sub) {
            f32x4 s[4];
            #pragma unroll
            for (int kt = 0; kt < 4; ++kt) {
                f32x4 acc = zero4;
                acc = __builtin_amdgcn_mfma_f32_16x16x32_bf16(ka[kt][0], qf[sub][0], acc, 0, 0, 0);
                acc = __builtin_amdgcn_mfma_f32_16x16x32_bf16(ka[kt][1], qf[sub][1], acc, 0, 0, 0);
                s[kt] = acc;
            }

            short8 pa[2];
            #pragma unroll
            for (int hh = 0; hh < 2; ++hh) {
                #pragma unroll
                for (int c = 0; c < 2; ++c) {
                    f32x4 sv = s[2 * hh + c];
                    #pragma unroll
                    for (int r = 0; r < 4; ++r) {
                        float p = __builtin_amdgcn_exp2f(sv[r]);
                        pa[hh][c * 4 + r] = f2bf(p);
                    }
                }
            }

            lacc[sub] = __builtin_amdgcn_mfma_f32_16x16x32_bf16(pa[0], onesv, lacc[sub], 0, 0, 0);
            lacc[sub] = __builtin_amdgcn_mfma_f32_16x16x32_bf16(pa[1], onesv, lacc[sub], 0, 0, 0);

            #pragma unroll
            for (int dg = 0; dg < 4; ++dg) {
                oacc[sub][dg] = __builtin_amdgcn_mfma_f32_16x16x32_bf16(pa[0], va[dg][0], oacc[sub][dg], 0, 0, 0);
                oacc[sub][dg] = __builtin_amdgcn_mfma_f32_16x16x32_bf16(pa[1], va[dg][1], oacc[sub][dg], 0, 0, 0);
            }
        }
    }

    #pragma unroll
    for (int sub = 0; sub < QSUB; ++sub) {
        float linv[4];
        #pragma unroll
        for (int r = 0; r < 4; ++r) linv[r] = 1.0f / lacc[sub][r];

        #pragma unroll
        for (int r = 0; r < 4; ++r) {
            short* orow = O + ((size_t)(b * T_DIM) + i0 + sub * 64 + w * 16 + quad * 4 + r) * C_DIM + h * HS;
            #pragma unroll
            for (int dg = 0; dg < 4; ++dg)
                orow[dg * 16 + l16] = f2bf(oacc[sub][dg][r] * linv[r]);
        }
    }
}

// ---------------------------------------------------------------------------
// ws layout (bytes), NB = 2*M*C = 16.8MB, WB = 2*C*C = 2.1MB:
//   [0]      xb bf16 (reused as Ob after QKV gemm)
//   [NB]     QKVb bf16 [M,3C]  (3*NB)
//   [4NB]    Vt bf16 [B*NH,HS,T]
//   [5NB]    W3b (Wq|Wk|Wv rows, 3*WB) | Wob (WB)      total 92.4MB
// ---------------------------------------------------------------------------
extern "C" void kernel_launch(void* const* d_in, const int* in_sizes, int n_in,
                              void* d_out, int out_size, void* d_ws, size_t ws_size,
                              hipStream_t stream) {
    const float* x  = (const float*)d_in[0];
    const float* Wk = (const float*)d_in[1];
    const float* Wq = (const float*)d_in[2];
    const float* Wv = (const float*)d_in[3];
    const float* Wo = (const float*)d_in[4];
    float* out = (float*)d_out;

    const int M = B_DIM * T_DIM;                       // 8192
    const size_t NE = (size_t)M * C_DIM;               // 8.4M
    const size_t NB = 2 * NE;                          // bytes
    const size_t WB = (size_t)2 * C_DIM * C_DIM;
    const size_t WE = (size_t)C_DIM * C_DIM;           // elements

    char* ws = (char*)d_ws;
    short* xb   = (short*)(ws);
    short* Ob   = xb;                                  // reuse after QKV gemm
    short* QKVb = (short*)(ws + NB);
    short* Vtb  = (short*)(ws + 4 * NB);
    short* W3b  = (short*)(ws + 5 * NB);               // [3C, C] rows: Wq|Wk|Wv (then Wob)
    short* Wob  = (short*)(ws + 5 * NB + 3 * WB);

    // casts: x, then all 4 weights in one launch (Wq pre-scaled by log2(e)/8)
    cast_bf16<<<(int)(NE / 8 / 256), 256, 0, stream>>>(x, xb, (int)(NE / 8), 1.0f);
    const int wn8 = (int)(WE / 8);                     // 131072
    cast4_bf16<<<dim3(wn8 / 256, 4), 256, 0, stream>>>(Wq, Wk, Wv, Wo, W3b, wn8);

    // fused QKV projection: [M,3C] = xb @ W3^T  (BM128xBN256, grid 768 = 3 rounds)
    gemm_bt_8ph<true><<<dim3((QKV_LD / 256) * (M / 128)), 512, 0, stream>>>(
        xb, W3b, QKVb, M, QKV_LD, C_DIM);

    // V transpose to [B*NH, HS, T]
    transpose_v<<<dim3(T_DIM / 64, B_DIM * NHEAD), 256, 0, stream>>>(
        QKVb + 2 * C_DIM, Vtb, QKV_LD);

    // attention (2x q-merge, 1024 blocks = 4 blocks/CU)
    attn_mfma3<<<dim3(T_DIM / (64 * QSUB), B_DIM * NHEAD), 256, 0, stream>>>(
        QKVb, QKVb + C_DIM, Vtb, Ob);

    // output projection (fp32 out; grid 256 = exactly 1 full round)
    gemm_bt_8ph<false><<<dim3((C_DIM / 256) * (M / 128)), 512, 0, stream>>>(
        Ob, Wob, out, M, C_DIM, C_DIM);
}

// Round 8
// 254.586 us; speedup vs baseline: 1.0199x; 1.0199x over previous
//
#include <hip/hip_runtime.h>
#include <hip/hip_bf16.h>
#include <cstddef>
#include <cstdint>

// Problem constants: B=4, T=2048, C=1024, NH=16, hs=64, M = B*T = 8192
#define B_DIM 4
#define T_DIM 2048
#define C_DIM 1024
#define NHEAD 16
#define HS    64
#define QKV_LD 3072   // fused QKV row stride (3*C)

// log2(e)/8 : folded into the Wq bf16 cast so QK^T emerges in exp2-domain.
#define QSCALE 0.18033688011112042f

typedef __attribute__((ext_vector_type(8))) short short8;   // 8 bf16 (MFMA A/B frag)
typedef __attribute__((ext_vector_type(4))) short short4v;  // 4 bf16 (8B store)
typedef __attribute__((ext_vector_type(4))) float f32x4;    // MFMA C/D frag

__device__ __forceinline__ short f2bf(float x) {
    __hip_bfloat16 b = __float2bfloat16(x);   // RNE
    return *reinterpret_cast<short*>(&b);
}

// async global->LDS, 16B per lane; LDS dest is wave-uniform base + lane*16.
__device__ __forceinline__ void load_lds16(const void* g, void* l) {
    __builtin_amdgcn_global_load_lds(
        (const __attribute__((address_space(1))) void*)(g),
        (__attribute__((address_space(3))) void*)(l),
        16, 0, 0);
}

// ---------------------------------------------------------------------------
// cast fp32 -> bf16 (with optional fp32 pre-scale), 8 elements/thread
// ---------------------------------------------------------------------------
__global__ __launch_bounds__(256) void cast_bf16(
    const float* __restrict__ in, short* __restrict__ out, int n8, float scale)
{
    int i = blockIdx.x * 256 + threadIdx.x;
    if (i >= n8) return;
    const float4* p = (const float4*)in + (size_t)i * 2;
    float4 a = p[0], b = p[1];
    short8 o;
    o[0]=f2bf(a.x*scale); o[1]=f2bf(a.y*scale); o[2]=f2bf(a.z*scale); o[3]=f2bf(a.w*scale);
    o[4]=f2bf(b.x*scale); o[5]=f2bf(b.y*scale); o[6]=f2bf(b.z*scale); o[7]=f2bf(b.w*scale);
    *((short8*)out + i) = o;
}

// 4 weight matrices (Wq|Wk|Wv|Wo) -> one contiguous bf16 region (W3b|Wob).
// blockIdx.y selects source; Wq gets QSCALE folded in.
__global__ __launch_bounds__(256) void cast4_bf16(
    const float* __restrict__ w0, const float* __restrict__ w1,
    const float* __restrict__ w2, const float* __restrict__ w3,
    short* __restrict__ out, int n8)
{
    int i = blockIdx.x * 256 + threadIdx.x;
    if (i >= n8) return;
    const int sel = blockIdx.y;
    const float* in = (sel == 0) ? w0 : (sel == 1) ? w1 : (sel == 2) ? w2 : w3;
    const float scale = (sel == 0) ? QSCALE : 1.0f;
    const float4* p = (const float4*)in + (size_t)i * 2;
    float4 a = p[0], b = p[1];
    short8 o;
    o[0]=f2bf(a.x*scale); o[1]=f2bf(a.y*scale); o[2]=f2bf(a.z*scale); o[3]=f2bf(a.w*scale);
    o[4]=f2bf(b.x*scale); o[5]=f2bf(b.y*scale); o[6]=f2bf(b.z*scale); o[7]=f2bf(b.w*scale);
    *((short8*)out + (size_t)sel * n8 + i) = o;
}

// ---------------------------------------------------------------------------
// 8-phase-style MFMA GEMM, BM=128 x BN=256: C[M,N] = A[M,K] @ B[N,K]^T,
// bf16 in, fp32 accum. BK=64, 8 waves (2M x 4N), 512 threads, acc[4][4]/wave.
// LDS 96 KiB double-buffered; grids are exact multiples of 256 (full rounds).
// OUT_MODE: 0 = fp32 out; 1 = bf16 out; 2 = QKV fused epilogue:
//   Q/K panels (n0 < 2048) -> bf16 to Cm[M,N];
//   V panels  (n0 >= 2048) -> bf16 TRANSPOSED direct to Vt[B*NH, HS, T]
//   (each thread's 4 acc rows = 4 consecutive tokens at fixed (head,d) ->
//    one contiguous 8B store; bit-identical to the old transpose_v pass).
// ---------------------------------------------------------------------------
template<int OUT_MODE>
__global__ __launch_bounds__(512, 2) void gemm_bt_8ph(
    const short* __restrict__ A,    // [M,K] bf16
    const short* __restrict__ Bm,   // [N,K] bf16
    void* __restrict__ Cm,          // [M,N]
    short* __restrict__ Vt,         // [B*NH, HS, T] (OUT_MODE==2 only)
    int M, int N, int K)
{
    __shared__ __align__(16) short lds[49152];   // 96 KiB

    // bijective XCD swizzle (gridDim.x % 8 == 0), then flat -> (bx,by)
    const int nbx = N >> 8;
    int wg = blockIdx.x;
    const int cpx = gridDim.x >> 3;
    wg = (wg & 7) * cpx + (wg >> 3);
    const int bx = wg % nbx, by = wg / nbx;
    const int m0 = by << 7, n0 = bx << 8;        // BM=128, BN=256

    const int t = threadIdx.x;
    const int w = t >> 6, lane = t & 63;
    const int l16 = lane & 15, quad = lane >> 4;
    const int wm = w >> 2, wn = w & 3;           // 2M x 4N waves

    // staging geometry: one call = 64 rows x 128B; thread -> (row, 16B chunk)
    const int rcall  = t >> 3;                   // 0..63
    const int schunk = (t & 7) ^ (rcall & 7);    // pre-swizzled source chunk
    const int dstoff = w * 512;                  // per-wave LDS base (w*8 rows * 64)

    const short* Ag = A  + (size_t)(m0 + rcall) * K + schunk * 8;
    const short* Bg = Bm + (size_t)(n0 + rcall) * K + schunk * 8;

    short* const Ab0 = lds;
    short* const Ab1 = lds + 8192;
    short* const Bb0 = lds + 16384;
    short* const Bb1 = lds + 32768;

    // frag read offsets (shorts), swizzled
    int aoff[4][2], boff[4][2];
    #pragma unroll
    for (int mf = 0; mf < 4; ++mf) {
        const int ar = wm * 64 + mf * 16 + l16;          // 0..127
        #pragma unroll
        for (int ks = 0; ks < 2; ++ks)
            aoff[mf][ks] = ar * 64 + (((ks * 4 + quad) ^ (ar & 7)) * 8);
    }
    #pragma unroll
    for (int nf = 0; nf < 4; ++nf) {
        const int br = wn * 64 + nf * 16 + l16;          // 0..255
        #pragma unroll
        for (int ks = 0; ks < 2; ++ks)
            boff[nf][ks] = br * 64 + (((ks * 4 + quad) ^ (br & 7)) * 8);
    }

    f32x4 acc[4][4];
    const f32x4 zero4 = {0.f, 0.f, 0.f, 0.f};
    #pragma unroll
    for (int mf = 0; mf < 4; ++mf)
        #pragma unroll
        for (int nf = 0; nf < 4; ++nf) acc[mf][nf] = zero4;

    const int NT = K >> 6;   // 64-wide K-tiles

    // one 64-row staging call
    #define ST64(gb, kt, ro, lb)                                               \
        load_lds16((gb) + (size_t)(ro) * K + (size_t)(kt) * 64,                \
                   (lb) + (ro) * 64 + dstoff)

    // prologue: t0.A (2), t0.B (4), t1.A (2)  -> 8 outstanding
    ST64(Ag, 0, 0, Ab0); ST64(Ag, 0, 64, Ab0);
    ST64(Bg, 0, 0, Bb0); ST64(Bg, 0, 64, Bb0);
    ST64(Bg, 0, 128, Bb0); ST64(Bg, 0, 192, Bb0);
    ST64(Ag, 1, 0, Ab1); ST64(Ag, 1, 64, Ab1);

    for (int kt = 0; kt < NT; ++kt) {
        short* Acur = (kt & 1) ? Ab1 : Ab0;
        short* Bcur = (kt & 1) ? Bb1 : Bb0;
        short* Bnx  = (kt & 1) ? Bb0 : Bb1;

        if (kt == NT - 1) asm volatile("s_waitcnt vmcnt(0)" ::: "memory");
        else              asm volatile("s_waitcnt vmcnt(2)" ::: "memory");
        __builtin_amdgcn_s_barrier();

        // ---- phase 0: B-frags (whole tile) + A-frags mf0,1 ----
        short8 bfr[4][2], af[2][2];
        #pragma unroll
        for (int nf = 0; nf < 4; ++nf)
            #pragma unroll
            for (int ks = 0; ks < 2; ++ks)
                bfr[nf][ks] = *(const short8*)(Bcur + boff[nf][ks]);
        #pragma unroll
        for (int mf = 0; mf < 2; ++mf)
            #pragma unroll
            for (int ks = 0; ks < 2; ++ks)
                af[mf][ks] = *(const short8*)(Acur + aoff[mf][ks]);

        if (kt + 1 < NT) { ST64(Bg, kt + 1, 0, Bnx); ST64(Bg, kt + 1, 64, Bnx); }

        __builtin_amdgcn_s_barrier();
        __builtin_amdgcn_s_setprio(1);
        #pragma unroll
        for (int mf = 0; mf < 2; ++mf)
            #pragma unroll
            for (int nf = 0; nf < 4; ++nf)
                #pragma unroll
                for (int ks = 0; ks < 2; ++ks)
                    acc[mf][nf] = __builtin_amdgcn_mfma_f32_16x16x32_bf16(
                        af[mf][ks], bfr[nf][ks], acc[mf][nf], 0, 0, 0);
        __builtin_amdgcn_s_setprio(0);
        __builtin_amdgcn_s_barrier();

        // ---- phase 1: A-frags mf2,3 ----
        short8 af2[2][2];
        #pragma unroll
        for (int mf = 0; mf < 2; ++mf)
            #pragma unroll
            for (int ks = 0; ks < 2; ++ks)
                af2[mf][ks] = *(const short8*)(Acur + aoff[2 + mf][ks]);

        if (kt + 1 < NT) { ST64(Bg, kt + 1, 128, Bnx); ST64(Bg, kt + 1, 192, Bnx); }

        __builtin_amdgcn_s_barrier();
        __builtin_amdgcn_s_setprio(1);
        #pragma unroll
        for (int mf = 0; mf < 2; ++mf)
            #pragma unroll
            for (int nf = 0; nf < 4; ++nf)
                #pragma unroll
                for (int ks = 0; ks < 2; ++ks)
                    acc[2 + mf][nf] = __builtin_amdgcn_mfma_f32_16x16x32_bf16(
                        af2[mf][ks], bfr[nf][ks], acc[2 + mf][nf], 0, 0, 0);
        __builtin_amdgcn_s_setprio(0);
        __builtin_amdgcn_s_barrier();

        // tail: just-freed A buffer -> prefetch (t+2).A
        if (kt + 2 < NT) {
            short* Aw = (kt & 1) ? Ab1 : Ab0;
            ST64(Ag, kt + 2, 0, Aw); ST64(Ag, kt + 2, 64, Aw);
        }
    }
    #undef ST64

    if (OUT_MODE == 2 && n0 >= 2 * C_DIM) {
        // V panel -> transposed write into Vt[B*NH, HS, T]
        const int b    = m0 >> 11;               // token block within one b
        const int tt0  = (m0 & 2047) + wm * 64 + quad * 4;
        #pragma unroll
        for (int nf = 0; nf < 4; ++nf) {
            const int vcol = (n0 - 2 * C_DIM) + wn * 64 + nf * 16 + l16;
            const int h    = vcol >> 6;          // head within b
            const int d    = vcol & 63;
            short* dcol = Vt + ((size_t)((b << 4) + h) * HS + d) * T_DIM;
            #pragma unroll
            for (int mf = 0; mf < 4; ++mf) {
                const int tt = tt0 + mf * 16;
                short4v o;
                o[0] = f2bf(acc[mf][nf][0]); o[1] = f2bf(acc[mf][nf][1]);
                o[2] = f2bf(acc[mf][nf][2]); o[3] = f2bf(acc[mf][nf][3]);
                *(short4v*)(dcol + tt) = o;
            }
        }
    } else {
        #pragma unroll
        for (int mf = 0; mf < 4; ++mf) {
            const int row_base = m0 + wm * 64 + mf * 16 + quad * 4;
            #pragma unroll
            for (int nf = 0; nf < 4; ++nf) {
                const int col = n0 + wn * 64 + nf * 16 + l16;
                #pragma unroll
                for (int r = 0; r < 4; ++r) {
                    const size_t idx = (size_t)(row_base + r) * N + col;
                    if (OUT_MODE != 0) ((short*)Cm)[idx] = f2bf(acc[mf][nf][r]);
                    else               ((float*)Cm)[idx] = acc[mf][nf][r];
                }
            }
        }
    }
}

// ---------------------------------------------------------------------------
// Flash attention v8: QSUB=2 (4 blocks/CU) + head-locality XCD swizzle.
//  - 1D grid 1024; xcd = bid&7 owns heads [xcd*8, xcd*8+8): per-XCD K+V
//    working set = 8 heads x 512KB = 4MB = one L2 -> K/V become L2-resident
//    instead of re-fetched from HBM by every XCD.
//  - [64][72] padded LDS (benign 2-way, beat the XOR swizzle in R6).
//  - Q pre-scaled by log2(e)/8 at the Wq cast -> exp is a bare v_exp_f32.
//  - Row-sum l computed by MFMA against a ones B-fragment.
// S^T trick: A=K-frag, B=Q-frag -> D[key][q]; K rows permuted kappa^-1 so
// exp'd S^T regs concatenate directly into the PV A-fragment. No-max softmax.
// ---------------------------------------------------------------------------
#define QSUB 2

__global__ __launch_bounds__(256, 4) void attn_mfma3(
    const short* __restrict__ Qb,    // [B,T,QKV_LD], Q cols (pre-scaled)
    const short* __restrict__ Kb,    // [B,T,QKV_LD], K cols
    const short* __restrict__ Vt,    // [B*NH, HS, T]
    short* __restrict__ O)           // [B,T,C] bf16
{
    // head-locality decode: 8 heads pinned per XCD, 16 q-chunks per head
    const int bid  = blockIdx.x;
    const int slot = bid >> 3;
    const int head = ((bid & 7) << 3) + (slot >> 4);
    const int i0   = (slot & 15) * (64 * QSUB);
    const int b = head >> 4, h = head & 15;

    const int t    = threadIdx.x;
    const int w    = t >> 6;
    const int lane = t & 63;
    const int l16  = lane & 15;
    const int quad = lane >> 4;

    __shared__ short Ks[64][72];     // [perm key][dim]
    __shared__ short Vts[64][72];    // [dim][key]

    short8 qf[QSUB][2];
    #pragma unroll
    for (int sub = 0; sub < QSUB; ++sub) {
        const short* qrow = Qb
            + ((size_t)(b * T_DIM) + i0 + sub * 64 + w * 16 + l16) * QKV_LD + h * HS;
        qf[sub][0] = *(const short8*)(qrow + quad * 8);
        qf[sub][1] = *(const short8*)(qrow + 32 + quad * 8);
    }

    short8 onesv;
    #pragma unroll
    for (int j = 0; j < 8; ++j) onesv[j] = (short)0x3F80;

    const f32x4 zero4 = {0.f, 0.f, 0.f, 0.f};
    f32x4 oacc[QSUB][4];
    f32x4 lacc[QSUB];
    #pragma unroll
    for (int sub = 0; sub < QSUB; ++sub) {
        #pragma unroll
        for (int dg = 0; dg < 4; ++dg) oacc[sub][dg] = zero4;
        lacc[sub] = zero4;
    }

    const int sr = t >> 2;
    const int sc = (t & 3) * 16;
    const int krow = (sr & 32) | ((sr & 4) << 2) | ((sr & 24) >> 1) | (sr & 3);
    const short* kgbase = Kb + (size_t)(b * T_DIM) * QKV_LD + h * HS;
    const short* vgbase = Vt + ((size_t)head * HS + sr) * T_DIM;

    for (int j0 = 0; j0 < T_DIM; j0 += 64) {
        __syncthreads();
        {
            const short* kp = kgbase + (size_t)(j0 + sr) * QKV_LD + sc;
            *(short8*)&Ks[krow][sc]     = *(const short8*)kp;
            *(short8*)&Ks[krow][sc + 8] = *(const short8*)(kp + 8);
            const short* vp = vgbase + j0 + sc;
            *(short8*)&Vts[sr][sc]      = *(const short8*)vp;
            *(short8*)&Vts[sr][sc + 8]  = *(const short8*)(vp + 8);
        }
        __syncthreads();

        // K/V MFMA fragments: read once, reuse for both q-subtiles
        short8 ka[4][2], va[4][2];
        #pragma unroll
        for (int kt = 0; kt < 4; ++kt) {
            ka[kt][0] = *(const short8*)&Ks[kt * 16 + l16][quad * 8];
            ka[kt][1] = *(const short8*)&Ks[kt * 16 + l16][32 + quad * 8];
            va[kt][0] = *(const short8*)&Vts[kt * 16 + l16][quad * 8];
            va[kt][1] = *(const short8*)&Vts[kt * 16 + l16][32 + quad * 8];
        }

        #pragma unroll
        for (int sub = 0; sub < QSUB; ++sub) {
            f32x4 s[4];
            #pragma unroll
            for (int kt = 0; kt < 4; ++kt) {
                f32x4 acc = zero4;
                acc = __builtin_amdgcn_mfma_f32_16x16x32_bf16(ka[kt][0], qf[sub][0], acc, 0, 0, 0);
                acc = __builtin_amdgcn_mfma_f32_16x16x32_bf16(ka[kt][1], qf[sub][1], acc, 0, 0, 0);
                s[kt] = acc;
            }

            short8 pa[2];
            #pragma unroll
            for (int hh = 0; hh < 2; ++hh) {
                #pragma unroll
                for (int c = 0; c < 2; ++c) {
                    f32x4 sv = s[2 * hh + c];
                    #pragma unroll
                    for (int r = 0; r < 4; ++r) {
                        float p = __builtin_amdgcn_exp2f(sv[r]);
                        pa[hh][c * 4 + r] = f2bf(p);
                    }
                }
            }

            lacc[sub] = __builtin_amdgcn_mfma_f32_16x16x32_bf16(pa[0], onesv, lacc[sub], 0, 0, 0);
            lacc[sub] = __builtin_amdgcn_mfma_f32_16x16x32_bf16(pa[1], onesv, lacc[sub], 0, 0, 0);

            #pragma unroll
            for (int dg = 0; dg < 4; ++dg) {
                oacc[sub][dg] = __builtin_amdgcn_mfma_f32_16x16x32_bf16(pa[0], va[dg][0], oacc[sub][dg], 0, 0, 0);
                oacc[sub][dg] = __builtin_amdgcn_mfma_f32_16x16x32_bf16(pa[1], va[dg][1], oacc[sub][dg], 0, 0, 0);
            }
        }
    }

    #pragma unroll
    for (int sub = 0; sub < QSUB; ++sub) {
        float linv[4];
        #pragma unroll
        for (int r = 0; r < 4; ++r) linv[r] = 1.0f / lacc[sub][r];

        #pragma unroll
        for (int r = 0; r < 4; ++r) {
            short* orow = O + ((size_t)(b * T_DIM) + i0 + sub * 64 + w * 16 + quad * 4 + r) * C_DIM + h * HS;
            #pragma unroll
            for (int dg = 0; dg < 4; ++dg)
                orow[dg * 16 + l16] = f2bf(oacc[sub][dg][r] * linv[r]);
        }
    }
}

// ---------------------------------------------------------------------------
// ws layout (bytes), NB = 2*M*C = 16.8MB, WB = 2*C*C = 2.1MB:
//   [0]      xb bf16 (reused as Ob after QKV gemm)
//   [NB]     QKVb bf16 [M,3C]  (3*NB; V cols unwritten — V goes direct to Vt)
//   [4NB]    Vt bf16 [B*NH,HS,T]
//   [5NB]    W3b (Wq|Wk|Wv rows, 3*WB) | Wob (WB)      total 92.4MB
// ---------------------------------------------------------------------------
extern "C" void kernel_launch(void* const* d_in, const int* in_sizes, int n_in,
                              void* d_out, int out_size, void* d_ws, size_t ws_size,
                              hipStream_t stream) {
    const float* x  = (const float*)d_in[0];
    const float* Wk = (const float*)d_in[1];
    const float* Wq = (const float*)d_in[2];
    const float* Wv = (const float*)d_in[3];
    const float* Wo = (const float*)d_in[4];
    float* out = (float*)d_out;

    const int M = B_DIM * T_DIM;                       // 8192
    const size_t NE = (size_t)M * C_DIM;               // 8.4M
    const size_t NB = 2 * NE;                          // bytes
    const size_t WB = (size_t)2 * C_DIM * C_DIM;
    const size_t WE = (size_t)C_DIM * C_DIM;           // elements

    char* ws = (char*)d_ws;
    short* xb   = (short*)(ws);
    short* Ob   = xb;                                  // reuse after QKV gemm
    short* QKVb = (short*)(ws + NB);
    short* Vtb  = (short*)(ws + 4 * NB);
    short* W3b  = (short*)(ws + 5 * NB);               // [3C, C] rows: Wq|Wk|Wv (then Wob)
    short* Wob  = (short*)(ws + 5 * NB + 3 * WB);

    // casts: x, then all 4 weights in one launch (Wq pre-scaled by log2(e)/8)
    cast_bf16<<<(int)(NE / 8 / 256), 256, 0, stream>>>(x, xb, (int)(NE / 8), 1.0f);
    const int wn8 = (int)(WE / 8);                     // 131072
    cast4_bf16<<<dim3(wn8 / 256, 4), 256, 0, stream>>>(Wq, Wk, Wv, Wo, W3b, wn8);

    // fused QKV projection + V-transpose epilogue (grid 768 = 3 full rounds)
    gemm_bt_8ph<2><<<dim3((QKV_LD / 256) * (M / 128)), 512, 0, stream>>>(
        xb, W3b, QKVb, Vtb, M, QKV_LD, C_DIM);

    // attention (2x q-merge, 1024 blocks = 4 blocks/CU, head-locality swizzle)
    attn_mfma3<<<dim3(T_DIM / (64 * QSUB) * B_DIM * NHEAD), 256, 0, stream>>>(
        QKVb, QKVb + C_DIM, Vtb, Ob);

    // output projection (fp32 out; grid 256 = exactly 1 full round)
    gemm_bt_8ph<0><<<dim3((C_DIM / 256) * (M / 128)), 512, 0, stream>>>(
        Ob, Wob, out, nullptr, M, C_DIM, C_DIM);
}